// Round 7
// baseline (36.423 us; speedup 1.0000x reference)
//
#include <hip/hip_runtime.h>
#include <hip/hip_bf16.h>

#define NEG_SLOPE 0.2f

typedef float f32x4 __attribute__((ext_vector_type(4)));

// bf16 helpers (RTN-even pack, shift-unpack)
__device__ __forceinline__ unsigned f2bf(float f) {
    unsigned u = __float_as_uint(f);
    return (u + 0x7FFFu + ((u >> 16) & 1u)) >> 16;
}
__device__ __forceinline__ float bf2f(unsigned h) {
    return __uint_as_float(h << 16);
}

// ---------------------------------------------------------------------------
// Folded 64-lane reduction (6 shuffles) — see R5. After it, lane c%8==0 in
// each 32-lane half holds component (c>>3) of (si_b, sj_b, si_p, sj_p).
// ---------------------------------------------------------------------------
__device__ __forceinline__ float fold_reduce(float sib, float sjb,
                                             float sip, float sjp,
                                             bool hiB, bool hiJ) {
    float g1 = hiB ? sib : sip;
    float r1 = __shfl_xor(g1, 16);
    float acc_i = (hiB ? sip : sib) + r1;
    float g2 = hiB ? sjb : sjp;
    float r2 = __shfl_xor(g2, 16);
    float acc_j = (hiB ? sjp : sjb) + r2;
    float g3 = hiJ ? acc_i : acc_j;
    float r3 = __shfl_xor(g3, 8);
    float acc = (hiJ ? acc_j : acc_i) + r3;
    acc += __shfl_xor(acc, 4);
    acc += __shfl_xor(acc, 2);
    acc += __shfl_xor(acc, 1);
    return acc;
}

__device__ __forceinline__ float dot4(const f32x4 z, const f32x4 v) {
    return z.x * v.x + z.y * v.y + z.z * v.z + z.w * v.w;
}

// Funnel the 4 components (lanes c=0,8,16,24 within each half) to lane c==0,
// pack as 4xbf16 into uint2 (8 B), store one entry per node.
__device__ __forceinline__ void pack_store(float acc, int c, bool valid,
                                           uint2* __restrict__ tab8, int node) {
    const float a1 = __shfl_down(acc, 8);
    const float a2 = __shfl_down(acc, 16);
    const float a3 = __shfl_down(acc, 24);
    if (c == 0 && valid) {
        uint2 p;
        p.x = f2bf(acc) | (f2bf(a1) << 16);
        p.y = f2bf(a2) | (f2bf(a3) << 16);
        tab8[node] = p;
    }
}

// ---------------------------------------------------------------------------
// Fused node kernel (structure identical to R6; only the tab store changed).
// ---------------------------------------------------------------------------
__global__ void __launch_bounds__(1024) fused_node_kernel(
        const float* __restrict__ W_b,
        const float* __restrict__ W_p,
        const float* __restrict__ a_b,
        const float* __restrict__ a_p,
        const f32x4* __restrict__ zb4,
        const f32x4* __restrict__ zp4,
        uint2*       __restrict__ tab8,   // [n_nodes] 4xbf16
        int n_nodes) {
    __shared__ float vsh[4][128];   // v1_b, v2_b, v1_p, v2_p
    __shared__ float psh[1024];

    const int tid = threadIdx.x;
    {   // prologue: vsh[vec][p] = sum_d W_ch[d][p] * a_ch[aoff + d]
        const int q   = tid >> 9;        // d-half (0: d<32, 1: d>=32)
        const int r   = tid & 511;       // output index (vec*128 + p)
        const int vec = r >> 7;
        const int p   = r & 127;
        const float* W = (vec >= 2) ? W_p : W_b;
        const float* a = ((vec >= 2) ? a_p : a_b) + (vec & 1) * 64 + 32 * q;
        const float* Wc = W + (32 * q) * 128 + p;
        float acc = 0.f;
        #pragma unroll
        for (int k = 0; k < 32; ++k)
            acc += Wc[k * 128] * a[k];
        psh[tid] = acc;
    }
    __syncthreads();
    if (tid < 512)
        vsh[tid >> 7][tid & 127] = psh[tid] + psh[512 + tid];
    __syncthreads();

    const int lane = tid & 63;
    const int h    = lane >> 5;                 // which node of the pair
    const int c    = lane & 31;                 // f32x4 column group
    const int wave   = (blockIdx.x * blockDim.x + tid) >> 6;
    const int nwaves = (gridDim.x * blockDim.x) >> 6;   // 8192
    const int npairs = (n_nodes + 1) >> 1;

    const f32x4 v1b = *reinterpret_cast<const f32x4*>(&vsh[0][4 * c]);
    const f32x4 v2b = *reinterpret_cast<const f32x4*>(&vsh[1][4 * c]);
    const f32x4 v1p = *reinterpret_cast<const f32x4*>(&vsh[2][4 * c]);
    const f32x4 v2p = *reinterpret_cast<const f32x4*>(&vsh[3][4 * c]);

    const bool hiB = (c & 16) != 0;
    const bool hiJ = (c & 8)  != 0;

    for (int pr = wave; pr < npairs; pr += 2 * nwaves) {
        const int pr2 = pr + nwaves;
        int node1 = 2 * pr + h;
        const bool valid1 = node1 < n_nodes;
        if (!valid1) node1 = n_nodes - 1;
        const f32x4 zb1 = zb4[node1 * 32 + c];
        const f32x4 zp1 = zp4[node1 * 32 + c];
        int node2 = 2 * pr2 + h;
        const bool run2 = pr2 < npairs;
        bool valid2 = run2 && (node2 < n_nodes);
        if (!valid2) node2 = n_nodes - 1;
        const f32x4 zb2 = zb4[node2 * 32 + c];
        const f32x4 zp2 = zp4[node2 * 32 + c];

        float acc1 = fold_reduce(dot4(zb1, v1b), dot4(zb1, v2b),
                                 dot4(zp1, v1p), dot4(zp1, v2p), hiB, hiJ);
        pack_store(acc1, c, valid1, tab8, node1);

        float acc2 = fold_reduce(dot4(zb2, v1b), dot4(zb2, v2b),
                                 dot4(zp2, v1p), dot4(zp2, v2p), hiB, hiJ);
        pack_store(acc2, c, valid2, tab8, node2);
    }
}

// ---------------------------------------------------------------------------
// Edge kernel: 2 edges/thread; gathers are now 8 B (uint2 of 4xbf16).
// ---------------------------------------------------------------------------
__device__ __forceinline__ float lrelu(float x) {
    return x >= 0.f ? x : NEG_SLOPE * x;
}

__device__ __forceinline__ float edge_score8(const uint2 ts, const uint2 td,
                                             float w0, float w1) {
    const float s_ib = bf2f(ts.x & 0xFFFFu), s_jb = bf2f(ts.x >> 16);
    const float s_ip = bf2f(ts.y & 0xFFFFu), s_jp = bf2f(ts.y >> 16);
    const float d_ib = bf2f(td.x & 0xFFFFu), d_jb = bf2f(td.x >> 16);
    const float d_ip = bf2f(td.y & 0xFFFFu), d_jp = bf2f(td.y >> 16);
    const float sb = 0.5f * (lrelu(s_ib + d_jb) + lrelu(d_ib + s_jb));
    const float sp = 0.5f * (lrelu(s_ip + d_jp) + lrelu(d_ip + s_jp));
    const float sc = w0 * sb + w1 * sp;            // TAU_MRF == 1
    return 1.f / (1.f + __expf(-sc));
}

__global__ void __launch_bounds__(256) edge_scores_kernel(
        const int*   __restrict__ src,
        const int*   __restrict__ dst,
        const uint2* __restrict__ tab8,
        const float* __restrict__ gamma_b,
        const float* __restrict__ gamma_p,
        float*       __restrict__ out,
        int n_edges) {
    const float gb = *gamma_b;
    const float gp = *gamma_p;
    const float w0 = 1.f / (1.f + __expf(gp - gb));  // softmax over 2 logits
    const float w1 = 1.f - w0;

    const int n_half = n_edges >> 1;
    const int stride = gridDim.x * blockDim.x;
    const int gid    = blockIdx.x * blockDim.x + threadIdx.x;

    const int2* src2 = (const int2*)src;
    const int2* dst2 = (const int2*)dst;
    float2*     out2 = (float2*)out;

    for (int i = gid; i < n_half; i += stride) {
        const int2 s = src2[i];
        const int2 d = dst2[i];
        const uint2 ts0 = tab8[s.x];
        const uint2 td0 = tab8[d.x];
        const uint2 ts1 = tab8[s.y];
        const uint2 td1 = tab8[d.y];
        float2 r;
        r.x = edge_score8(ts0, td0, w0, w1);
        r.y = edge_score8(ts1, td1, w0, w1);
        out2[i] = r;
    }
    const int tail_base = n_half << 1;
    for (int e = tail_base + gid; e < n_edges; e += stride) {
        out[e] = edge_score8(tab8[src[e]], tab8[dst[e]], w0, w1);
    }
}

extern "C" void kernel_launch(void* const* d_in, const int* in_sizes, int n_in,
                              void* d_out, int out_size, void* d_ws, size_t ws_size,
                              hipStream_t stream) {
    const float* z_beh  = (const float*)d_in[0];
    const float* z_pref = (const float*)d_in[1];
    const float* W_b    = (const float*)d_in[2];
    const float* W_p    = (const float*)d_in[3];
    const float* a_b    = (const float*)d_in[4];
    const float* a_p    = (const float*)d_in[5];
    const float* g_b    = (const float*)d_in[6];
    const float* g_p    = (const float*)d_in[7];
    const int*   ei     = (const int*)d_in[8];   // [2, E] int32

    const int n_nodes = in_sizes[0] / 128;
    const int n_edges = in_sizes[8] / 2;

    uint2* tab8 = (uint2*)d_ws;                  // n_nodes * 8 B

    fused_node_kernel<<<512, 1024, 0, stream>>>(
        W_b, W_p, a_b, a_p,
        (const f32x4*)z_beh, (const f32x4*)z_pref, tab8, n_nodes);

    const int n_half = n_edges >> 1;
    int eblocks = (n_half + 255) / 256;
    if (eblocks > 4096) eblocks = 4096;
    if (eblocks < 1) eblocks = 1;
    edge_scores_kernel<<<eblocks, 256, 0, stream>>>(
        ei, ei + n_edges, tab8, g_b, g_p, (float*)d_out, n_edges);
}